// Round 4
// baseline (397673.828 us; speedup 1.0000x reference)
//
#include <hip/hip_runtime.h>
#include <cstddef>

// ---------------- problem constants ----------------
// B=32, T_IN=512, T_OUT=800, N_MEL=80, ENC=512, ARNN=DRNN=1024, PRE=256,
// ATT=128, LOCF=32, LOCK=31.  4*ARNN = 4096 gate rows.

// ---------------- workspace layout (float offsets) ----------------
constexpr size_t WT_ATT = 0;                            // [1792][4096]
constexpr size_t WT_DEC = WT_ATT + 1792ull * 4096;      // [2560][4096]
constexpr size_t PREN_O = WT_DEC + 2560ull * 4096;      // [800][32][256]
constexpr size_t PMEMT  = PREN_O + 800ull * 32 * 256;   // [32][128][512]
constexpr size_t W1T    = PMEMT + 32ull * 128 * 512;    // [80][256]
constexpr size_t W2T    = W1T + 80 * 256;               // [256][256]
constexpr size_t QWT    = W2T + 256 * 256;              // [1024][128]
constexpr size_t PWT    = QWT + 1024 * 128;             // [1536][96] (cols 0..79 mel, 80 gate)
constexpr size_t MEMWT  = PWT + 1536 * 96;              // [512][128]
constexpr size_t XATT   = MEMWT + 512 * 128;            // [2][32][1792]  (pren|actx|ah)
constexpr size_t XDEC   = XATT + 2ull * 32 * 1792;      // [32][2560]     (ah|dh|actx)
constexpr size_t AH_O   = XDEC + 32ull * 2560;          // [32][1024]
constexpr size_t AC_O   = AH_O + 32 * 1024;
constexpr size_t DH_O   = AC_O + 32 * 1024;
constexpr size_t DC_O   = DH_O + 32 * 1024;
constexpr size_t AW_O   = DC_O + 32 * 1024;             // [32][512]
constexpr size_t AWC_O  = AW_O + 32 * 512;              // [32][512]
constexpr size_t ACTX_O = AWC_O + 32 * 512;             // [2][32][512]
constexpr size_t ENER_O = ACTX_O + 2ull * 32 * 512;     // [32][512]
constexpr size_t ZATT_O = ENER_O + 32 * 512;            // [3][32][4096]
constexpr size_t ZDEC_O = ZATT_O + 3ull * 32 * 4096;    // [4][32][4096]
constexpr size_t BAR_O  = ZDEC_O + 4ull * 32 * 4096;    // barrier counter (1 u32, 64B pad)

constexpr size_t MEL_OUT = 0;                 // [32][80][800]
constexpr size_t GATE_OUT = 2048000;          // [32][800]
constexpr size_t ALIGN_OUT = 2073600;         // [32][800][512]

// ---------------- coherent (MALL-bypass) accessors ----------------
// Communicated data uses relaxed agent-scope atomics: sc-flagged vmem ops that
// bypass L1/L2 to the MALL (cross-XCD coherence point). NO fences anywhere —
// read-only weights therefore stay resident in each XCD's L2 across steps.
// Ordering: __syncthreads() before barrier-arrival drains vmcnt(0), so all
// bypass stores are complete at the MALL before the arrive-add is visible.
__device__ __forceinline__ float gload(const float* p_) {
  return __hip_atomic_load(p_, __ATOMIC_RELAXED, __HIP_MEMORY_SCOPE_AGENT);
}
__device__ __forceinline__ void gstore(float* p_, float v) {
  __hip_atomic_store(p_, v, __ATOMIC_RELAXED, __HIP_MEMORY_SCOPE_AGENT);
}

// ---------------- software grid barrier (fence-free) ----------------
__device__ __forceinline__ void gsync(unsigned* __restrict__ bar, unsigned& epoch) {
  __syncthreads();  // drains vmcnt(0): bypass stores complete at MALL
  if (threadIdx.x == 0) {
    __hip_atomic_fetch_add(bar, 1u, __ATOMIC_RELAXED, __HIP_MEMORY_SCOPE_AGENT);
    ++epoch;
    const unsigned target = epoch * 256u;
    while (__hip_atomic_load(bar, __ATOMIC_RELAXED, __HIP_MEMORY_SCOPE_AGENT) < target) {
      __builtin_amdgcn_s_sleep(8);
    }
  }
  __syncthreads();
}

// ---------------- helpers ----------------
__device__ __forceinline__ float sigf(float x) {
  float cx = fminf(fmaxf(x, -30.f), 30.f);
  return 1.f / (1.f + __expf(-cx));
}
__device__ __forceinline__ float tanh_f(float x) {
  float cx = fminf(fmaxf(x, -15.f), 15.f);
  float e = __expf(2.f * cx);
  return (e - 1.f) / (e + 1.f);
}

// Z_partial[b][4096] for rows gb*64..gb*64+63, K range [klo,khi).
// X: [32][xstride] (communicated -> bypass loads), WT: [K][4096] (cached).
__device__ __forceinline__ void gemm_partial(
    const float* __restrict__ X, int xstride, const float* __restrict__ WT,
    int klo, int khi, float* __restrict__ zp, int gb, int tid, float* xs) {
  const int b = tid & 31, gt = tid >> 5;
  const int g0 = gb * 64 + gt * 8;
  float acc0 = 0, acc1 = 0, acc2 = 0, acc3 = 0, acc4 = 0, acc5 = 0, acc6 = 0, acc7 = 0;
  for (int kc = klo; kc < khi; kc += 256) {
    const int cn = (khi - kc < 256) ? (khi - kc) : 256;
    __syncthreads();
    if (tid < cn) {
      for (int r = 0; r < 32; ++r)
        xs[r * 260 + tid] = gload(X + (size_t)r * xstride + kc + tid);
    }
    __syncthreads();
    const float* wb = WT + (size_t)kc * 4096 + g0;
    for (int kk = 0; kk < cn; kk += 4) {
      const float4 xv = *(const float4*)(xs + b * 260 + kk);
      const float* w0p = wb + (size_t)kk * 4096;
#define GSTEP(J, XJ)                                                     \
  {                                                                      \
    const float4 wA = *(const float4*)(w0p + (size_t)(J) * 4096);        \
    const float4 wB = *(const float4*)(w0p + (size_t)(J) * 4096 + 4);    \
    acc0 = fmaf(XJ, wA.x, acc0); acc1 = fmaf(XJ, wA.y, acc1);            \
    acc2 = fmaf(XJ, wA.z, acc2); acc3 = fmaf(XJ, wA.w, acc3);            \
    acc4 = fmaf(XJ, wB.x, acc4); acc5 = fmaf(XJ, wB.y, acc5);            \
    acc6 = fmaf(XJ, wB.z, acc6); acc7 = fmaf(XJ, wB.w, acc7);            \
  }
      GSTEP(0, xv.x) GSTEP(1, xv.y) GSTEP(2, xv.z) GSTEP(3, xv.w)
#undef GSTEP
    }
  }
  float* zr = zp + (size_t)b * 4096 + g0;
  gstore(zr + 0, acc0); gstore(zr + 1, acc1);
  gstore(zr + 2, acc2); gstore(zr + 3, acc3);
  gstore(zr + 4, acc4); gstore(zr + 5, acc5);
  gstore(zr + 6, acc6); gstore(zr + 7, acc7);
}

// ---------------- setup kernels ----------------
__global__ __launch_bounds__(256) void k_small(
    const float* __restrict__ w1, const float* __restrict__ w2,
    const float* __restrict__ qw, const float* __restrict__ memw,
    const float* __restrict__ projw, const float* __restrict__ gatew,
    float* __restrict__ ws) {
  size_t i = (size_t)blockIdx.x * 256 + threadIdx.x;
  if (i < 20480) { size_t j = i & 255, m = i >> 8; ws[W1T + m * 256 + j] = w1[j * 80 + m]; return; }
  i -= 20480;
  if (i < 65536) { size_t j = i & 255, k = i >> 8; ws[W2T + k * 256 + j] = w2[j * 256 + k]; return; }
  i -= 65536;
  if (i < 131072) { size_t j = i & 127, k = i >> 7; ws[QWT + k * 128 + j] = qw[j * 1024 + k]; return; }
  i -= 131072;
  if (i < 65536) { size_t a = i & 127, e = i >> 7; ws[MEMWT + e * 128 + a] = memw[a * 512 + e]; return; }
  i -= 65536;
  if (i < 147456) {
    size_t o = i % 96, k = i / 96;
    float v = 0.f;
    if (o < 80) v = projw[o * 1536 + k];
    else if (o == 80) v = gatew[k];
    ws[PWT + k * 96 + o] = v;
  }
}

__global__ __launch_bounds__(256) void k_wt_att(const float* __restrict__ wih,
                                                const float* __restrict__ whh,
                                                float* __restrict__ ws) {
  const size_t i = (size_t)blockIdx.x * 256 + threadIdx.x;  // = k*4096 + g
  const size_t g = i & 4095, k = i >> 12;
  ws[WT_ATT + i] = (k < 768) ? wih[g * 768 + k] : whh[g * 1024 + (k - 768)];
}

__global__ __launch_bounds__(256) void k_wt_dec(const float* __restrict__ wih,
                                                const float* __restrict__ whh,
                                                float* __restrict__ ws) {
  const size_t i = (size_t)blockIdx.x * 256 + threadIdx.x;
  const size_t g = i & 4095, k = i >> 12;
  float v;
  if (k < 1024) v = wih[g * 1536 + k];                       // ah part of wih
  else if (k < 2048) v = whh[g * 1024 + (k - 1024)];         // dh (whh)
  else v = wih[g * 1536 + 1024 + (k - 2048)];                // actx part of wih
  ws[WT_DEC + i] = v;
}

__global__ __launch_bounds__(256) void k_xdec0(float* __restrict__ ws) {
  const int i = blockIdx.x * 256 + threadIdx.x;  // < 32768
  const int b = i >> 10, j = i & 1023;
  ws[XDEC + (size_t)b * 2560 + 1024 + j] = 0.f;
}

__global__ __launch_bounds__(256) void k_prenet(const float* __restrict__ din,
                                                float* __restrict__ ws) {
  __shared__ float h1[8][257];
  const int tg = blockIdx.x, b = blockIdx.y, j = threadIdx.x;
  float acc[8] = {0, 0, 0, 0, 0, 0, 0, 0};
  for (int m = 0; m < 80; ++m) {
    const float w = ws[W1T + m * 256 + j];
#pragma unroll
    for (int q = 0; q < 8; ++q) {
      const int t = tg * 8 + q;
      const float x = (t > 0) ? din[((size_t)b * 80 + m) * 800 + (t - 1)] : 0.f;
      acc[q] = fmaf(x, w, acc[q]);
    }
  }
#pragma unroll
  for (int q = 0; q < 8; ++q) h1[q][j] = fmaxf(acc[q], 0.f);
  __syncthreads();
  float a2[8] = {0, 0, 0, 0, 0, 0, 0, 0};
  for (int k = 0; k < 256; ++k) {
    const float w = ws[W2T + k * 256 + j];
#pragma unroll
    for (int q = 0; q < 8; ++q) a2[q] = fmaf(h1[q][k], w, a2[q]);
  }
#pragma unroll
  for (int q = 0; q < 8; ++q) {
    const int t = tg * 8 + q;
    ws[PREN_O + ((size_t)t * 32 + b) * 256 + j] = fmaxf(a2[q], 0.f);
  }
}

__global__ __launch_bounds__(256) void k_pmem(const float* __restrict__ mem,
                                              float* __restrict__ ws) {
  __shared__ float mt[16 * 516];
  const int b = blockIdx.x, tc = blockIdx.y, tid = threadIdx.x;
  const int ti0 = tc * 16;
  for (int i = tid; i < 16 * 128; i += 256) {
    const int r = i >> 7, c = i & 127;
    *(float4*)(mt + r * 516 + c * 4) =
        *(const float4*)(mem + ((size_t)b * 512 + ti0 + r) * 512 + c * 4);
  }
  __syncthreads();
  const int a = tid & 127, th = tid >> 7;
  float acc[8] = {0, 0, 0, 0, 0, 0, 0, 0};
  for (int e = 0; e < 512; ++e) {
    const float w = ws[MEMWT + (size_t)e * 128 + a];
#pragma unroll
    for (int q = 0; q < 8; ++q) acc[q] = fmaf(w, mt[(th * 8 + q) * 516 + e], acc[q]);
  }
#pragma unroll
  for (int q = 0; q < 8; ++q)
    ws[PMEMT + ((size_t)b * 128 + a) * 512 + ti0 + th * 8 + q] = acc[q];
}

// ---------------- main persistent kernel ----------------
struct TP {
  const float *mem, *abih, *abhh, *lconv, *llw, *vw, *dbih, *dbhh, *projb, *gateb;
  const int* lens;
  float* ws;
  float* out;
};

__global__ __launch_bounds__(256) void taco_main(TP p) {
  __shared__ float smem[8320];
  float* const ws = p.ws;
  unsigned* const bar = (unsigned*)(ws + BAR_O);
  unsigned epoch = 0;
  const int bid = blockIdx.x, tid = threadIdx.x;

#pragma unroll 1
  for (int t = 0; t <= 800; ++t) {
    const int par = t & 1;
    // ---- S1: att-GEMM(t) [192 blocks] ; dec-actx-GEMM(t-1) [64 blocks]
    if (bid < 192) {
      if (t < 800) {
        const int ks = bid >> 6, gb = bid & 63;
        const int klo = ks * 600, khi = (ks == 2) ? 1792 : klo + 600;
        gemm_partial(ws + XATT + (size_t)par * 57344, 1792, ws + WT_ATT, klo, khi,
                     ws + ZATT_O + (size_t)ks * 131072, gb, tid, smem);
      }
    } else if (t > 0) {
      gemm_partial(ws + XDEC, 2560, ws + WT_DEC, 2048, 2560,
                   ws + ZDEC_O + 3ull * 131072, bid - 192, tid, smem);
    }
    gsync(bar, epoch);

    // ---- S2: att-cell(t) [128 blocks] ; dec-cell(t-1) [128 blocks]
    if (bid < 128) {
      if (t < 800) {
        const int idx = bid * 256 + tid, b = idx >> 10, j = idx & 1023;
        const float* zp = ws + ZATT_O + (size_t)b * 4096;
        float zi = gload(zp + j) + gload(zp + 131072 + j) + gload(zp + 262144 + j) +
                   p.abih[j] + p.abhh[j];
        float zf = gload(zp + 1024 + j) + gload(zp + 131072 + 1024 + j) +
                   gload(zp + 262144 + 1024 + j) + p.abih[1024 + j] + p.abhh[1024 + j];
        float zg = gload(zp + 2048 + j) + gload(zp + 131072 + 2048 + j) +
                   gload(zp + 262144 + 2048 + j) + p.abih[2048 + j] + p.abhh[2048 + j];
        float zo = gload(zp + 3072 + j) + gload(zp + 131072 + 3072 + j) +
                   gload(zp + 262144 + 3072 + j) + p.abih[3072 + j] + p.abhh[3072 + j];
        const float cp = ws[AC_O + (size_t)b * 1024 + j];   // block-private: cached
        const float ct = sigf(zf) * cp + sigf(zi) * tanh_f(zg);
        const float h = sigf(zo) * tanh_f(ct);
        ws[AC_O + (size_t)b * 1024 + j] = ct;               // block-private: cached
        gstore(ws + AH_O + (size_t)b * 1024 + j, h);
        gstore(ws + XATT + (size_t)((t + 1) & 1) * 57344 + (size_t)b * 1792 + 768 + j, h);
        gstore(ws + XDEC + (size_t)b * 2560 + j, h);
      }
    } else if (t > 0) {
      const int idx = (bid - 128) * 256 + tid, b = idx >> 10, j = idx & 1023;
      const float* zp = ws + ZDEC_O + (size_t)b * 4096;
      float zi = gload(zp + j) + gload(zp + 131072 + j) + gload(zp + 262144 + j) +
                 gload(zp + 393216 + j) + p.dbih[j] + p.dbhh[j];
      float zf = gload(zp + 1024 + j) + gload(zp + 131072 + 1024 + j) +
                 gload(zp + 262144 + 1024 + j) + gload(zp + 393216 + 1024 + j) +
                 p.dbih[1024 + j] + p.dbhh[1024 + j];
      float zg = gload(zp + 2048 + j) + gload(zp + 131072 + 2048 + j) +
                 gload(zp + 262144 + 2048 + j) + gload(zp + 393216 + 2048 + j) +
                 p.dbih[2048 + j] + p.dbhh[2048 + j];
      float zo = gload(zp + 3072 + j) + gload(zp + 131072 + 3072 + j) +
                 gload(zp + 262144 + 3072 + j) + gload(zp + 393216 + 3072 + j) +
                 p.dbih[3072 + j] + p.dbhh[3072 + j];
      const float cp = ws[DC_O + (size_t)b * 1024 + j];     // block-private: cached
      const float ct = sigf(zf) * cp + sigf(zi) * tanh_f(zg);
      const float h = sigf(zo) * tanh_f(ct);
      ws[DC_O + (size_t)b * 1024 + j] = ct;                 // block-private: cached
      gstore(ws + DH_O + (size_t)b * 1024 + j, h);
      gstore(ws + XDEC + (size_t)b * 2560 + 1024 + j, h);
    }
    gsync(bar, epoch);

    // ---- S3: dec-[ah|dh]-GEMM(t) [192] ; energies(t)+pq+proj(t-1) [64]
    if (bid < 192) {
      if (t < 800) {
        const int ks = bid >> 6, gb = bid & 63;
        const int klo = ks * 684, khi = (ks == 2) ? 2048 : klo + 684;
        gemm_partial(ws + XDEC, 2560, ws + WT_DEC, klo, khi,
                     ws + ZDEC_O + (size_t)ks * 131072, gb, tid, smem);
      }
    } else {
      const int e = bid - 192, b = e >> 1, half = e & 1;
      const int tbase = half * 256;
      float* sm_pqp = smem;        // 256
      float* sm_pq = smem + 256;   // 128
      float* sm_a0 = smem + 384;   // 288 (aw halo)
      float* sm_a1 = smem + 672;   // 288 (awc halo)
      if (t < 800) {
        {  // pq partials: pq[b][j] = sum_k ah[b][k]*qw[j][k]
          const int j = tid & 127, kh = tid >> 7;
          float acc = 0;
          const float* qcol = ws + QWT + j;
          const float* ahr = ws + AH_O + (size_t)b * 1024 + kh * 512;
          for (int k = 0; k < 512; ++k)
            acc = fmaf(qcol[(size_t)(kh * 512 + k) * 128], gload(ahr + k), acc);
          sm_pqp[tid] = acc;
        }
        for (int i = tid; i < 286; i += 256) {
          const int ti = tbase - 15 + i;
          const bool ok = (unsigned)ti < 512u;
          sm_a0[i] = ok ? gload(ws + AW_O + (size_t)b * 512 + ti) : 0.f;
          sm_a1[i] = ok ? gload(ws + AWC_O + (size_t)b * 512 + ti) : 0.f;
        }
        __syncthreads();
        if (tid < 128) sm_pq[tid] = sm_pqp[tid] + sm_pqp[128 + tid];
        __syncthreads();
        // per-thread: one t_in position
        float wa[31], wcc[31];
#pragma unroll
        for (int k2 = 0; k2 < 31; ++k2) {
          wa[k2] = sm_a0[tid + k2];
          wcc[k2] = sm_a1[tid + k2];
        }
        float loc[32];
#pragma unroll 1
        for (int f = 0; f < 32; ++f) {
          const float* wf = p.lconv + f * 62;
          float acc = 0;
#pragma unroll
          for (int k2 = 0; k2 < 31; ++k2) acc = fmaf(wa[k2], wf[k2], acc);
#pragma unroll
          for (int k2 = 0; k2 < 31; ++k2) acc = fmaf(wcc[k2], wf[31 + k2], acc);
          loc[f] = acc;
        }
        const int ti = tbase + tid;
        const float* pmcol = ws + PMEMT + (size_t)b * 128 * 512 + ti;
        float acc_e = 0;
#pragma unroll 1
        for (int a = 0; a < 128; ++a) {
          float s = sm_pq[a] + pmcol[(size_t)a * 512];
          const float* la = p.llw + a * 32;
#pragma unroll
          for (int f = 0; f < 32; ++f) s = fmaf(loc[f], la[f], s);
          acc_e = fmaf(p.vw[a], tanh_f(s), acc_e);
        }
        gstore(ws + ENER_O + (size_t)b * 512 + ti, (ti < p.lens[b]) ? acc_e : -1e9f);
      }
      if (t > 0) {  // proj(t-1): 81 outputs, K=1536 split into 6 segments
        __syncthreads();
        const int oi = tid / 6, ksg = tid - oi * 6;
        float part = 0.f;
        if (oi < 41) {
          const int o = half * 41 + oi;  // o==81 reads zero pad, discarded
          const int k0 = ksg * 256;
          const float* xh = ws + DH_O + (size_t)b * 1024;
          const float* xa = ws + ACTX_O + (size_t)((t - 1) & 1) * 16384 + (size_t)b * 512;
          const float* wcol = ws + PWT + o;
          for (int k = k0; k < k0 + 256; ++k) {
            const float x = (k < 1024) ? gload(xh + k) : gload(xa + (k - 1024));
            part = fmaf(x, wcol[(size_t)k * 96], part);
          }
        }
        __syncthreads();
        smem[tid] = part;
        __syncthreads();
        const int cnt = half ? 40 : 41;
        if (tid < cnt) {
          const int o = half * 41 + tid;
          float ssum = 0;
#pragma unroll
          for (int q = 0; q < 6; ++q) ssum += smem[tid * 6 + q];
          ssum += (o < 80) ? p.projb[o] : p.gateb[0];
          if (o < 80) p.out[MEL_OUT + ((size_t)b * 80 + o) * 800 + (t - 1)] = ssum;
          else p.out[GATE_OUT + (size_t)b * 800 + (t - 1)] = ssum;
        }
      }
    }
    gsync(bar, epoch);

    // ---- S4: softmax + context  [256 blocks: b = bid>>3, d-chunk = bid&7]
    if (t < 800) {
      const int b = bid >> 3, dc8 = bid & 7;
      float* sm_p = smem;        // 512
      float* sm_r = smem + 512;  // 256
      float* sm_c = smem + 768;  // 256
      const float e0 = gload(ws + ENER_O + (size_t)b * 512 + tid);
      const float e1 = gload(ws + ENER_O + (size_t)b * 512 + 256 + tid);
      sm_r[tid] = fmaxf(e0, e1);
      __syncthreads();
      for (int s = 128; s > 0; s >>= 1) {
        if (tid < s) sm_r[tid] = fmaxf(sm_r[tid], sm_r[tid + s]);
        __syncthreads();
      }
      const float mx = sm_r[0];
      __syncthreads();
      const float p0 = __expf(e0 - mx), p1 = __expf(e1 - mx);
      sm_p[tid] = p0;
      sm_p[256 + tid] = p1;
      sm_r[tid] = p0 + p1;
      __syncthreads();
      for (int s = 128; s > 0; s >>= 1) {
        if (tid < s) sm_r[tid] += sm_r[tid + s];
        __syncthreads();
      }
      const float inv = 1.f / sm_r[0];
      const int tseg = tid >> 6, dl = tid & 63;
      const int d = dc8 * 64 + dl;
      const float* mrow = p.mem + ((size_t)b * 512 + tseg * 128) * 512 + d;  // cached
      float acc = 0;
      for (int i = 0; i < 128; ++i) acc = fmaf(sm_p[tseg * 128 + i], mrow[(size_t)i * 512], acc);
      sm_c[tid] = acc;
      __syncthreads();
      if (tid < 64) {
        const float v =
            (sm_c[tid] + sm_c[64 + tid] + sm_c[128 + tid] + sm_c[192 + tid]) * inv;
        const int dd = dc8 * 64 + tid;
        gstore(ws + ACTX_O + (size_t)(t & 1) * 16384 + (size_t)b * 512 + dd, v);
        gstore(ws + XATT + (size_t)((t + 1) & 1) * 57344 + (size_t)b * 1792 + 256 + dd, v);
        gstore(ws + XDEC + (size_t)b * 2560 + 2048 + dd, v);
      }
      if (dc8 == 0) {
        const float a0 = p0 * inv, a1 = p1 * inv;
        gstore(ws + AW_O + (size_t)b * 512 + tid, a0);
        gstore(ws + AW_O + (size_t)b * 512 + 256 + tid, a1);
        gstore(ws + AWC_O + (size_t)b * 512 + tid,
               gload(ws + AWC_O + (size_t)b * 512 + tid) + a0);
        gstore(ws + AWC_O + (size_t)b * 512 + 256 + tid,
               gload(ws + AWC_O + (size_t)b * 512 + 256 + tid) + a1);
        p.out[ALIGN_OUT + ((size_t)b * 800 + t) * 512 + tid] = a0;
        p.out[ALIGN_OUT + ((size_t)b * 800 + t) * 512 + 256 + tid] = a1;
      }
      if (dc8 == 1 && t + 1 < 800) {
        gstore(ws + XATT + (size_t)((t + 1) & 1) * 57344 + (size_t)b * 1792 + tid,
               ws[PREN_O + ((size_t)(t + 1) * 32 + b) * 256 + tid]);  // pren: cached read
      }
    }
    gsync(bar, epoch);
  }
}

// ---------------- launch ----------------
extern "C" void kernel_launch(void* const* d_in, const int* in_sizes, int n_in,
                              void* d_out, int out_size, void* d_ws, size_t ws_size,
                              hipStream_t stream) {
  (void)in_sizes; (void)n_in; (void)out_size; (void)ws_size;
  const float* mem = (const float*)d_in[0];
  const float* decin = (const float*)d_in[1];
  const float* w1 = (const float*)d_in[2];
  const float* w2 = (const float*)d_in[3];
  const float* awih = (const float*)d_in[4];
  const float* awhh = (const float*)d_in[5];
  const float* abih = (const float*)d_in[6];
  const float* abhh = (const float*)d_in[7];
  const float* qw = (const float*)d_in[8];
  const float* memw = (const float*)d_in[9];
  const float* vw = (const float*)d_in[10];
  const float* lconv = (const float*)d_in[11];
  const float* llw = (const float*)d_in[12];
  const float* dwih = (const float*)d_in[13];
  const float* dwhh = (const float*)d_in[14];
  const float* dbih = (const float*)d_in[15];
  const float* dbhh = (const float*)d_in[16];
  const float* projw = (const float*)d_in[17];
  const float* projb = (const float*)d_in[18];
  const float* gatew = (const float*)d_in[19];
  const float* gateb = (const float*)d_in[20];
  const int* lens = (const int*)d_in[21];
  float* ws = (float*)d_ws;
  float* out = (float*)d_out;

  // zero state (AH..ACTX contiguous = 196608 floats), Xatt[0] (pren[0]==0),
  // and the barrier counter (monotonic within one launch).
  hipMemsetAsync(ws + AH_O, 0, 196608 * sizeof(float), stream);
  hipMemsetAsync(ws + XATT, 0, 57344 * sizeof(float), stream);
  hipMemsetAsync(ws + BAR_O, 0, 256, stream);

  k_small<<<1680, 256, 0, stream>>>(w1, w2, qw, memw, projw, gatew, ws);
  k_wt_att<<<28672, 256, 0, stream>>>(awih, awhh, ws);
  k_wt_dec<<<40960, 256, 0, stream>>>(dwih, dwhh, ws);
  k_prenet<<<dim3(100, 32), 256, 0, stream>>>(decin, ws);
  k_xdec0<<<128, 256, 0, stream>>>(ws);
  k_pmem<<<dim3(32, 32), 256, 0, stream>>>(mem, ws);

  TP tp{mem, abih, abhh, lconv, llw, vw, dbih, dbhh, projb, gateb, lens, ws, out};
  taco_main<<<256, 256, 0, stream>>>(tp);
}

// Round 6
// 321615.918 us; speedup vs baseline: 1.2365x; 1.2365x over previous
//
#include <hip/hip_runtime.h>
#include <cstddef>

// ---------------- problem constants ----------------
// B=32, T_IN=512, T_OUT=800, N_MEL=80, ENC=512, ARNN=DRNN=1024, PRE=256,
// ATT=128, LOCF=32, LOCK=31.  4*ARNN = 4096 gate rows.

// ---------------- workspace layout (float offsets) ----------------
constexpr size_t WT_ATT = 0;                         // [1792][4096]
constexpr size_t WT_DEC = 7340032;                   // [2560][4096]
constexpr size_t PREN_O = 17825792;                  // [800][32][256]
constexpr size_t PMEMT  = 24379392;                  // [32][128][512]
constexpr size_t W1T    = 26476544;                  // [80][256]
constexpr size_t W2T    = 26497024;                  // [256][256]
constexpr size_t QWT    = 26562560;                  // [1024][128]
constexpr size_t PWT    = 26693632;                  // [1536][96]
constexpr size_t MEMWT  = 26841088;                  // [512][128]
constexpr size_t XATT   = 26906624;                  // [2][32][1792] (pren|actx|ah)
constexpr size_t XDEC   = 27021312;                  // [2][32][2560] (ah|dh|actx)
constexpr size_t AH_O   = 27185152;                  // [32][1024]
constexpr size_t AC_O   = 27217920;                  // [32][1024] block-private
constexpr size_t DH_O   = 27250688;                  // [32][1024]
constexpr size_t DC_O   = 27283456;                  // [32][1024] block-private
constexpr size_t AWC_O  = 27316224;                  // [2][32][512]
constexpr size_t ACTX_O = 27348992;                  // [2][32][512]
constexpr size_t ENER_O = 27381760;                  // [32][512]
constexpr size_t LOC_O  = 27398144;                  // [32][512][32]
constexpr size_t BAR_O  = 27922432;                  // 4224 u32

constexpr size_t MEL_OUT = 0;                 // [32][80][800]
constexpr size_t GATE_OUT = 2048000;          // [32][800]
constexpr size_t ALIGN_OUT = 2073600;         // [32][800][512]

// ---------------- coherent (MALL-bypass) accessors ----------------
__device__ __forceinline__ float gload(const float* p_) {
  return __hip_atomic_load(p_, __ATOMIC_RELAXED, __HIP_MEMORY_SCOPE_AGENT);
}
__device__ __forceinline__ void gstore(float* p_, float v) {
  __hip_atomic_store(p_, v, __ATOMIC_RELAXED, __HIP_MEMORY_SCOPE_AGENT);
}

// ---------------- contention-free grid barrier (no fences) ----------------
// 8 arrival counters (one add per block) + leader fan-out to 256 private
// release lines. Every spin polls a line with exactly one writer and one
// reader. __syncthreads() before arrival drains vmcnt, so all bypass stores
// are at the MALL before the arrive-add can be observed.
__device__ __forceinline__ void gsync(float* ws, unsigned& epoch) {
  unsigned* cnt = (unsigned*)(ws + BAR_O);         // cnt[g*16], g<8
  unsigned* rel = (unsigned*)(ws + BAR_O) + 128;   // rel[i*16], i<256
  __syncthreads();
  const int tid = threadIdx.x, bid = blockIdx.x;
  ++epoch;
  if (tid == 0)
    __hip_atomic_fetch_add(&cnt[(bid & 7) * 16], 1u, __ATOMIC_RELAXED,
                           __HIP_MEMORY_SCOPE_AGENT);
  if (bid == 0) {
    if (tid < 64) {
      const unsigned tgt = epoch * 32u;
      bool done;
      do {
        unsigned v = (tid < 8) ? __hip_atomic_load(&cnt[tid * 16], __ATOMIC_RELAXED,
                                                   __HIP_MEMORY_SCOPE_AGENT)
                               : tgt;
        done = v >= tgt;
        if (!done) __builtin_amdgcn_s_sleep(2);
      } while (__ballot(done) != ~0ull);
      for (int r = tid; r < 256; r += 64)
        __hip_atomic_store(&rel[r * 16], epoch, __ATOMIC_RELAXED,
                           __HIP_MEMORY_SCOPE_AGENT);
    }
  } else if (tid == 0) {
    while (__hip_atomic_load(&rel[bid * 16], __ATOMIC_RELAXED,
                             __HIP_MEMORY_SCOPE_AGENT) < epoch)
      __builtin_amdgcn_s_sleep(4);
  }
  __syncthreads();
}

// ---------------- helpers ----------------
__device__ __forceinline__ float sigf(float x) {
  float cx = fminf(fmaxf(x, -30.f), 30.f);
  return 1.f / (1.f + __expf(-cx));
}
__device__ __forceinline__ float tanh_f(float x) {
  float cx = fminf(fmaxf(x, -15.f), 15.f);
  float e = __expf(2.f * cx);
  return (e - 1.f) / (e + 1.f);
}

// ---------------- fused GEMM + LSTM cell ----------------
// Block g owns gate rows {gate*1024 + g*8 .. +7} for all 4 gates, all 32 b.
// Full-K dot products -> z stays in registers/LDS -> cell computed locally.
// X: [32][K] bypass-loaded (communicated); WT: [K][4096] plain cached.
__device__ __forceinline__ void fused_block(
    const float* __restrict__ X, const int K, const float* __restrict__ WT,
    const int g, const float* __restrict__ bih, const float* __restrict__ bhh,
    float* __restrict__ cst, float* __restrict__ d0, const int s0,
    float* __restrict__ d1, const int s1, float* __restrict__ d2, const int s2,
    const int tid, float* __restrict__ xs) {
  const int b = tid & 31, rg = tid >> 5;
  const int gate = rg >> 1, rh = (rg & 1) * 4;
  const int colbase = gate * 1024 + g * 8 + rh;
  const int col = tid & 127, r0 = (tid >> 7) * 16;
  float4 acc = make_float4(0.f, 0.f, 0.f, 0.f);
  float pf[16];
#pragma unroll
  for (int i = 0; i < 16; ++i) pf[i] = gload(X + (size_t)(r0 + i) * K + col);
  const int nc = K >> 7;  // chunks of 128
#pragma unroll 1
  for (int c = 0; c < nc; ++c) {
    float* xw = xs + (c & 1) * 4224;
#pragma unroll
    for (int i = 0; i < 16; ++i) xw[(r0 + i) * 132 + col] = pf[i];
    __syncthreads();
    if (c + 1 < nc) {
      const float* Xn = X + (size_t)(c + 1) * 128 + col;
#pragma unroll
      for (int i = 0; i < 16; ++i) pf[i] = gload(Xn + (size_t)(r0 + i) * K);
    }
    const float* xp = xw + b * 132;
    const float* wp = WT + (size_t)c * 128 * 4096 + colbase;
#pragma unroll 8
    for (int kk = 0; kk < 128; kk += 4) {
      const float4 xv = *(const float4*)(xp + kk);
      const float4 w0 = *(const float4*)(wp);
      const float4 w1 = *(const float4*)(wp + 4096);
      const float4 w2 = *(const float4*)(wp + 8192);
      const float4 w3 = *(const float4*)(wp + 12288);
      acc.x = fmaf(w0.x, xv.x, acc.x); acc.y = fmaf(w0.y, xv.x, acc.y);
      acc.z = fmaf(w0.z, xv.x, acc.z); acc.w = fmaf(w0.w, xv.x, acc.w);
      acc.x = fmaf(w1.x, xv.y, acc.x); acc.y = fmaf(w1.y, xv.y, acc.y);
      acc.z = fmaf(w1.z, xv.y, acc.z); acc.w = fmaf(w1.w, xv.y, acc.w);
      acc.x = fmaf(w2.x, xv.z, acc.x); acc.y = fmaf(w2.y, xv.z, acc.y);
      acc.z = fmaf(w2.z, xv.z, acc.z); acc.w = fmaf(w2.w, xv.z, acc.w);
      acc.x = fmaf(w3.x, xv.w, acc.x); acc.y = fmaf(w3.y, xv.w, acc.y);
      acc.z = fmaf(w3.z, xv.w, acc.z); acc.w = fmaf(w3.w, xv.w, acc.w);
      wp += 16384;
    }
    __syncthreads();
  }
  // gate exchange via LDS (overlays xs buffer 0; safe after final sync)
  float* zs = xs;  // [32 rows][33]
  zs[(gate * 8 + rh + 0) * 33 + b] = acc.x;
  zs[(gate * 8 + rh + 1) * 33 + b] = acc.y;
  zs[(gate * 8 + rh + 2) * 33 + b] = acc.z;
  zs[(gate * 8 + rh + 3) * 33 + b] = acc.w;
  __syncthreads();
  const int jj = tid & 7, bb = tid >> 3;
  const int j = g * 8 + jj;
  const float zi = zs[jj * 33 + bb] + bih[j] + bhh[j];
  const float zf = zs[(8 + jj) * 33 + bb] + bih[1024 + j] + bhh[1024 + j];
  const float zg = zs[(16 + jj) * 33 + bb] + bih[2048 + j] + bhh[2048 + j];
  const float zo = zs[(24 + jj) * 33 + bb] + bih[3072 + j] + bhh[3072 + j];
  const float cp = cst[(size_t)bb * 1024 + j];  // block-private: plain cached
  const float ct = sigf(zf) * cp + sigf(zi) * tanh_f(zg);
  const float h = sigf(zo) * tanh_f(ct);
  cst[(size_t)bb * 1024 + j] = ct;
  gstore(d0 + (size_t)bb * s0 + j, h);
  if (d1) gstore(d1 + (size_t)bb * s1 + j, h);
  if (d2) gstore(d2 + (size_t)bb * s2 + j, h);
}

// ---------------- setup kernels ----------------
__global__ __launch_bounds__(256) void k_small(
    const float* __restrict__ w1, const float* __restrict__ w2,
    const float* __restrict__ qw, const float* __restrict__ memw,
    const float* __restrict__ projw, const float* __restrict__ gatew,
    float* __restrict__ ws) {
  size_t i = (size_t)blockIdx.x * 256 + threadIdx.x;
  if (i < 20480) { size_t j = i & 255, m = i >> 8; ws[W1T + m * 256 + j] = w1[j * 80 + m]; return; }
  i -= 20480;
  if (i < 65536) { size_t j = i & 255, k = i >> 8; ws[W2T + k * 256 + j] = w2[j * 256 + k]; return; }
  i -= 65536;
  if (i < 131072) { size_t j = i & 127, k = i >> 7; ws[QWT + k * 128 + j] = qw[j * 1024 + k]; return; }
  i -= 131072;
  if (i < 65536) { size_t a = i & 127, e = i >> 7; ws[MEMWT + e * 128 + a] = memw[a * 512 + e]; return; }
  i -= 65536;
  if (i < 147456) {
    size_t o = i % 96, k = i / 96;
    float v = 0.f;
    if (o < 80) v = projw[o * 1536 + k];
    else if (o == 80) v = gatew[k];
    ws[PWT + k * 96 + o] = v;
  }
}

__global__ __launch_bounds__(256) void k_wt_att(const float* __restrict__ wih,
                                                const float* __restrict__ whh,
                                                float* __restrict__ ws) {
  const size_t i = (size_t)blockIdx.x * 256 + threadIdx.x;  // = k*4096 + g
  const size_t g = i & 4095, k = i >> 12;
  ws[WT_ATT + i] = (k < 768) ? wih[g * 768 + k] : whh[g * 1024 + (k - 768)];
}

__global__ __launch_bounds__(256) void k_wt_dec(const float* __restrict__ wih,
                                                const float* __restrict__ whh,
                                                float* __restrict__ ws) {
  const size_t i = (size_t)blockIdx.x * 256 + threadIdx.x;
  const size_t g = i & 4095, k = i >> 12;
  float v;
  if (k < 1024) v = wih[g * 1536 + k];
  else if (k < 2048) v = whh[g * 1024 + (k - 1024)];
  else v = wih[g * 1536 + 1024 + (k - 2048)];
  ws[WT_DEC + i] = v;
}

__global__ __launch_bounds__(256) void k_prenet(const float* __restrict__ din,
                                                float* __restrict__ ws) {
  __shared__ float h1[8][257];
  const int tg = blockIdx.x, b = blockIdx.y, j = threadIdx.x;
  float acc[8] = {0, 0, 0, 0, 0, 0, 0, 0};
  for (int m = 0; m < 80; ++m) {
    const float w = ws[W1T + m * 256 + j];
#pragma unroll
    for (int q = 0; q < 8; ++q) {
      const int t = tg * 8 + q;
      const float x = (t > 0) ? din[((size_t)b * 80 + m) * 800 + (t - 1)] : 0.f;
      acc[q] = fmaf(x, w, acc[q]);
    }
  }
#pragma unroll
  for (int q = 0; q < 8; ++q) h1[q][j] = fmaxf(acc[q], 0.f);
  __syncthreads();
  float a2[8] = {0, 0, 0, 0, 0, 0, 0, 0};
  for (int k = 0; k < 256; ++k) {
    const float w = ws[W2T + k * 256 + j];
#pragma unroll
    for (int q = 0; q < 8; ++q) a2[q] = fmaf(h1[q][k], w, a2[q]);
  }
#pragma unroll
  for (int q = 0; q < 8; ++q) {
    const int t = tg * 8 + q;
    ws[PREN_O + ((size_t)t * 32 + b) * 256 + j] = fmaxf(a2[q], 0.f);
  }
}

__global__ __launch_bounds__(256) void k_pmem(const float* __restrict__ mem,
                                              float* __restrict__ ws) {
  __shared__ float mt[16 * 516];
  const int b = blockIdx.x, tc = blockIdx.y, tid = threadIdx.x;
  const int ti0 = tc * 16;
  for (int i = tid; i < 16 * 128; i += 256) {
    const int r = i >> 7, c = i & 127;
    *(float4*)(mt + r * 516 + c * 4) =
        *(const float4*)(mem + ((size_t)b * 512 + ti0 + r) * 512 + c * 4);
  }
  __syncthreads();
  const int a = tid & 127, th = tid >> 7;
  float acc[8] = {0, 0, 0, 0, 0, 0, 0, 0};
  for (int e = 0; e < 512; ++e) {
    const float w = ws[MEMWT + (size_t)e * 128 + a];
#pragma unroll
    for (int q = 0; q < 8; ++q) acc[q] = fmaf(w, mt[(th * 8 + q) * 516 + e], acc[q]);
  }
#pragma unroll
  for (int q = 0; q < 8; ++q)
    ws[PMEMT + ((size_t)b * 128 + a) * 512 + ti0 + th * 8 + q] = acc[q];
}

// ---------------- main persistent kernel ----------------
struct TP {
  const float *mem, *abih, *abhh, *lconv, *llw, *vw, *dbih, *dbhh, *projb, *gateb;
  const int* lens;
  float* ws;
  float* out;
};

__global__ __launch_bounds__(256, 1) void taco_main(TP p) {
  __shared__ float smem[8448];
  float* const ws = p.ws;
  unsigned epoch = 0;
  const int bid = blockIdx.x, tid = threadIdx.x;

#pragma unroll 1
  for (int t = 0; t <= 800; ++t) {
    const int par = t & 1, nxt = (t + 1) & 1, prv = (t - 1) & 1;
    // ======== P1: att-fused(t) [0..127] | dec-fused(t-1) [128..255] ========
    if (bid < 128) {
      if (t < 800)
        fused_block(ws + XATT + (size_t)par * 57344, 1792, ws + WT_ATT, bid,
                    p.abih, p.abhh, ws + AC_O,
                    ws + AH_O, 1024,
                    ws + XATT + (size_t)nxt * 57344 + 768, 1792,
                    ws + XDEC + (size_t)par * 81920, 2560, tid, smem);
    } else {
      if (t > 0)
        fused_block(ws + XDEC + (size_t)prv * 81920, 2560, ws + WT_DEC, bid - 128,
                    p.dbih, p.dbhh, ws + DC_O,
                    ws + DH_O, 1024,
                    ws + XDEC + (size_t)par * 81920 + 1024, 2560,
                    nullptr, 0, tid, smem);
    }
    gsync(ws, epoch);

    // ======== P2: energies(t) [0..127] | proj(t-1) [128..159] ========
    if (bid < 128) {
      if (t < 800) {
        const int b = bid >> 2, q = bid & 3;
        float* sa = smem;            // 1024 (ah)
        float* sloc = smem + 1024;   // 128*33
        float* pqp = smem + 5248;    // 256
        float* pq = smem + 5504;     // 128
        float* sme = smem + 5632;    // 256
#pragma unroll
        for (int i = 0; i < 4; ++i)
          sa[tid + 256 * i] = gload(ws + AH_O + (size_t)b * 1024 + tid + 256 * i);
#pragma unroll
        for (int ii = 0; ii < 16; ++ii) {
          const int flat = tid + 256 * ii;
          sloc[(flat >> 5) * 33 + (flat & 31)] =
              gload(ws + LOC_O + (size_t)b * 16384 + (size_t)q * 4096 + flat);
        }
        __syncthreads();
        {  // pq[j] = ah . qw[j], K split in 2
          const int j = tid & 127, kh = tid >> 7;
          float acc = 0;
          const float* qb = ws + QWT + (size_t)kh * 512 * 128 + j;
          const float* ab = sa + kh * 512;
          for (int k = 0; k < 512; ++k) acc = fmaf(qb[(size_t)k * 128], ab[k], acc);
          pqp[tid] = acc;
        }
        __syncthreads();
        if (tid < 128) pq[tid] = pqp[tid] + pqp[128 + tid];
        __syncthreads();
        const int ti_l = tid & 127, th = tid >> 7;
        float lr[32];
#pragma unroll
        for (int f = 0; f < 32; ++f) lr[f] = sloc[ti_l * 33 + f];
        const float* pmb =
            ws + PMEMT + (size_t)b * 65536 + (size_t)(th * 64) * 512 + q * 128 + ti_l;
        float acc_e = 0;
#pragma unroll 1
        for (int a0 = 0; a0 < 64; ++a0) {
          const int a = th * 64 + a0;
          float s = pq[a] + pmb[(size_t)a0 * 512];
          const float* la = p.llw + a * 32;
#pragma unroll
          for (int f = 0; f < 32; ++f) s = fmaf(lr[f], la[f], s);
          acc_e = fmaf(p.vw[a], tanh_f(s), acc_e);
        }
        sme[tid] = acc_e;
        __syncthreads();
        if (tid < 128) {
          const int ti = q * 128 + tid;
          const float e = sme[tid] + sme[128 + tid];
          gstore(ws + ENER_O + (size_t)b * 512 + ti, (ti < p.lens[b]) ? e : -1e9f);
        }
      }
    } else if (bid < 160) {
      if (t > 0) {  // proj(t-1) for b = bid-128: 81 outs, K=1536
        const int b = bid - 128;
        float* sx = smem;          // 1536
        float* sred = smem + 1536; // 256
#pragma unroll
        for (int i = 0; i < 6; ++i) {
          const int flat = tid + 256 * i;
          sx[flat] = (flat < 1024)
                         ? gload(ws + DH_O + (size_t)b * 1024 + flat)
                         : gload(ws + ACTX_O + (size_t)prv * 16384 + (size_t)b * 512 +
                                 (flat - 1024));
        }
        __syncthreads();
        float part = 0.f;
        const int o = tid / 3, ks = tid - o * 3;
        if (o < 81) {
          const float* wcol = ws + PWT + o;
          const int k0 = ks * 512;
          for (int k = k0; k < k0 + 512; ++k)
            part = fmaf(sx[k], wcol[(size_t)k * 96], part);
        }
        sred[tid] = part;
        __syncthreads();
        if (tid < 81) {
          float ssum = sred[tid * 3] + sred[tid * 3 + 1] + sred[tid * 3 + 2];
          ssum += (tid < 80) ? p.projb[tid] : p.gateb[0];
          if (tid < 80)
            p.out[MEL_OUT + ((size_t)b * 80 + tid) * 800 + (t - 1)] = ssum;
          else
            p.out[GATE_OUT + (size_t)b * 800 + (t - 1)] = ssum;
        }
      }
    }
    gsync(ws, epoch);

    // ======== P3: softmax + context + awc + conv(t+1)  [all 256] ========
    if (t < 800) {
      const int b = bid >> 3, dc8 = bid & 7;
      float* se = smem;           // 512
      float* red = smem + 512;    // 256
      float* sp = smem + 768;     // 512
      float* sc = smem + 1280;    // 256
      float* saw = smem + 1536;   // 128 (aw halo)
      float* sawh = smem + 1664;  // 128 (awc_new halo)
      float* slc = smem + 1792;   // 1984 (conv weights)
      se[tid] = gload(ws + ENER_O + (size_t)b * 512 + tid);
      se[256 + tid] = gload(ws + ENER_O + (size_t)b * 512 + 256 + tid);
      for (int i = tid; i < 1984; i += 256) slc[i] = p.lconv[i];
      __syncthreads();
      red[tid] = fmaxf(se[tid], se[256 + tid]);
      __syncthreads();
      for (int s = 128; s > 0; s >>= 1) {
        if (tid < s) red[tid] = fmaxf(red[tid], red[tid + s]);
        __syncthreads();
      }
      const float mx = red[0];
      __syncthreads();
      const float p0 = __expf(se[tid] - mx), p1 = __expf(se[256 + tid] - mx);
      sp[tid] = p0;
      sp[256 + tid] = p1;
      red[tid] = p0 + p1;
      __syncthreads();
      for (int s = 128; s > 0; s >>= 1) {
        if (tid < s) red[tid] += red[tid + s];
        __syncthreads();
      }
      const float inv = 1.f / red[0];
      // context: this block covers d in [dc8*64, +64)
      const int tseg = tid >> 6, dl = tid & 63;
      const float* mrow = p.mem + ((size_t)b * 512 + tseg * 128) * 512 + dc8 * 64 + dl;
      float acc = 0;
      for (int i = 0; i < 128; ++i)
        acc = fmaf(sp[tseg * 128 + i], mrow[(size_t)i * 512], acc);
      sc[tid] = acc;
      // aw / awc_new halo for conv
      const int base = dc8 * 64;
      for (int i = tid; i < 95; i += 256) {
        const int x = base - 15 + i;
        const bool ok = (unsigned)x < 512u;
        const float awx = ok ? sp[x] * inv : 0.f;
        saw[i] = awx;
        sawh[i] = awx + (ok ? gload(ws + AWC_O + (size_t)par * 16384 +
                                    (size_t)b * 512 + x)
                            : 0.f);
      }
      __syncthreads();
      if (tid < 64) {
        const float v = (sc[tid] + sc[64 + tid] + sc[128 + tid] + sc[192 + tid]) * inv;
        const int dd = base + tid;
        gstore(ws + ACTX_O + (size_t)par * 16384 + (size_t)b * 512 + dd, v);
        gstore(ws + XATT + (size_t)nxt * 57344 + (size_t)b * 1792 + 256 + dd, v);
        // dec-step t (iteration t+1, P1) reads XDEC[par] -> actx(t) must land
        // in XDEC[par] (was nxt in R5: one-step-stale context = the R5 bug).
        gstore(ws + XDEC + (size_t)par * 81920 + (size_t)b * 2560 + 2048 + dd, v);
        gstore(ws + AWC_O + (size_t)nxt * 16384 + (size_t)b * 512 + dd, sawh[15 + tid]);
        p.out[ALIGN_OUT + ((size_t)b * 800 + t) * 512 + dd] = sp[dd] * inv;
      }
      if (t + 1 < 800) {
        // conv for step t+1 over this block's t_in slice
        const int f = tid & 31, tig = tid >> 5;
#pragma unroll 1
        for (int tt = 0; tt < 8; ++tt) {
          const int til = tig + tt * 8;
          float a2 = 0;
#pragma unroll
          for (int k2 = 0; k2 < 31; ++k2) a2 = fmaf(saw[til + k2], slc[f * 62 + k2], a2);
#pragma unroll
          for (int k2 = 0; k2 < 31; ++k2)
            a2 = fmaf(sawh[til + k2], slc[f * 62 + 31 + k2], a2);
          gstore(ws + LOC_O + (size_t)b * 16384 + (size_t)(base + til) * 32 + f, a2);
        }
        // pren(t+1) -> XATT[nxt]
        if (dc8 < 4 && tid < 64) {
          const int cc = dc8 * 64 + tid;
          gstore(ws + XATT + (size_t)nxt * 57344 + (size_t)b * 1792 + cc,
                 ws[PREN_O + ((size_t)(t + 1) * 32 + b) * 256 + cc]);
        }
      }
    }
    gsync(ws, epoch);
  }
}

// ---------------- launch ----------------
extern "C" void kernel_launch(void* const* d_in, const int* in_sizes, int n_in,
                              void* d_out, int out_size, void* d_ws, size_t ws_size,
                              hipStream_t stream) {
  (void)in_sizes; (void)n_in; (void)out_size; (void)ws_size;
  const float* mem = (const float*)d_in[0];
  const float* decin = (const float*)d_in[1];
  const float* w1 = (const float*)d_in[2];
  const float* w2 = (const float*)d_in[3];
  const float* awih = (const float*)d_in[4];
  const float* awhh = (const float*)d_in[5];
  const float* abih = (const float*)d_in[6];
  const float* abhh = (const float*)d_in[7];
  const float* qw = (const float*)d_in[8];
  const float* memw = (const float*)d_in[9];
  const float* vw = (const float*)d_in[10];
  const float* lconv = (const float*)d_in[11];
  const float* llw = (const float*)d_in[12];
  const float* dwih = (const float*)d_in[13];
  const float* dwhh = (const float*)d_in[14];
  const float* dbih = (const float*)d_in[15];
  const float* dbhh = (const float*)d_in[16];
  const float* projw = (const float*)d_in[17];
  const float* projb = (const float*)d_in[18];
  const float* gatew = (const float*)d_in[19];
  const float* gateb = (const float*)d_in[20];
  const int* lens = (const int*)d_in[21];
  float* ws = (float*)d_ws;
  float* out = (float*)d_out;

  // zero: X buffers (pren(0)=0, ah(-1)=0, dh(-1)=0, actx(-1)=0),
  // state AH..DC, AWC, ACTX, ENER, LOC, and barrier lines.
  hipMemsetAsync(ws + XATT, 0, (114688 + 163840) * sizeof(float), stream);
  hipMemsetAsync(ws + AH_O, 0, 737280 * sizeof(float), stream);
  hipMemsetAsync(ws + BAR_O, 0, 4224 * sizeof(unsigned), stream);

  k_small<<<1680, 256, 0, stream>>>(w1, w2, qw, memw, projw, gatew, ws);
  k_wt_att<<<28672, 256, 0, stream>>>(awih, awhh, ws);
  k_wt_dec<<<40960, 256, 0, stream>>>(dwih, dwhh, ws);
  k_prenet<<<dim3(100, 32), 256, 0, stream>>>(decin, ws);
  k_pmem<<<dim3(32, 32), 256, 0, stream>>>(mem, ws);

  TP tp{mem, abih, abhh, lconv, llw, vw, dbih, dbhh, projb, gateb, lens, ws, out};
  taco_main<<<256, 256, 0, stream>>>(tp);
}

// Round 7
// 192744.104 us; speedup vs baseline: 2.0632x; 1.6686x over previous
//
#include <hip/hip_runtime.h>
#include <cstddef>

// ---------------- problem constants ----------------
// B=32, T_IN=512, T_OUT=800, N_MEL=80, ENC=512, ARNN=DRNN=1024, PRE=256,
// ATT=128, LOCF=32, LOCK=31.  4*ARNN = 4096 gate rows.

// ---------------- workspace layout (float offsets) ----------------
// WT_ATT: [128 blocks][1792 k][32 cols]  (col = gate*8 + jj)
// WT_DEC: [128 blocks][2560 k][32 cols]
constexpr size_t WT_ATT = 0;                         // 7340032
constexpr size_t WT_DEC = 7340032;                   // +10485760
constexpr size_t PREN_O = 17825792;                  // [800][32][256]
constexpr size_t PMEMT  = 24379392;                  // [32][128][512]
constexpr size_t W1T    = 26476544;                  // [80][256]
constexpr size_t W2T    = 26497024;                  // [256][256]
constexpr size_t QWT    = 26562560;                  // [1024][128]
constexpr size_t PWT    = 26693632;                  // [1536][96]
constexpr size_t MEMWT  = 26841088;                  // [512][128]
constexpr size_t XATT   = 26906624;                  // [2][32][1792] (pren|actx|ah)
constexpr size_t XDEC   = 27021312;                  // [2][32][2560] (ah|dh|actx)
constexpr size_t AH_O   = 27185152;                  // [32][1024]
constexpr size_t AC_O   = 27217920;                  // [32][1024] block-private
constexpr size_t DH_O   = 27250688;                  // [32][1024]
constexpr size_t DC_O   = 27283456;                  // [32][1024] block-private
constexpr size_t AWC_O  = 27316224;                  // [2][32][512]
constexpr size_t ACTX_O = 27348992;                  // [2][32][512]
constexpr size_t ENER_O = 27381760;                  // [32][512]
constexpr size_t LOC_O  = 27398144;                  // [32][512][32]
constexpr size_t BAR_O  = 27922432;                  // 4224 u32

constexpr size_t MEL_OUT = 0;                 // [32][80][800]
constexpr size_t GATE_OUT = 2048000;          // [32][800]
constexpr size_t ALIGN_OUT = 2073600;         // [32][800][512]

// ---------------- coherent (MALL-bypass) accessors ----------------
__device__ __forceinline__ float gload(const float* p_) {
  return __hip_atomic_load(p_, __ATOMIC_RELAXED, __HIP_MEMORY_SCOPE_AGENT);
}
__device__ __forceinline__ void gstore(float* p_, float v) {
  __hip_atomic_store(p_, v, __ATOMIC_RELAXED, __HIP_MEMORY_SCOPE_AGENT);
}

// ---------------- contention-free grid barrier (no fences) ----------------
__device__ __forceinline__ void gsync(float* ws, unsigned& epoch) {
  unsigned* cnt = (unsigned*)(ws + BAR_O);         // cnt[g*16], g<8
  unsigned* rel = (unsigned*)(ws + BAR_O) + 128;   // rel[i*16], i<256
  __syncthreads();
  const int tid = threadIdx.x, bid = blockIdx.x;
  ++epoch;
  if (tid == 0)
    __hip_atomic_fetch_add(&cnt[(bid & 7) * 16], 1u, __ATOMIC_RELAXED,
                           __HIP_MEMORY_SCOPE_AGENT);
  if (bid == 0) {
    if (tid < 64) {
      const unsigned tgt = epoch * 32u;
      bool done;
      do {
        unsigned v = (tid < 8) ? __hip_atomic_load(&cnt[tid * 16], __ATOMIC_RELAXED,
                                                   __HIP_MEMORY_SCOPE_AGENT)
                               : tgt;
        done = v >= tgt;
        if (!done) __builtin_amdgcn_s_sleep(2);
      } while (__ballot(done) != ~0ull);
      for (int r = tid; r < 256; r += 64)
        __hip_atomic_store(&rel[r * 16], epoch, __ATOMIC_RELAXED,
                           __HIP_MEMORY_SCOPE_AGENT);
    }
  } else if (tid == 0) {
    while (__hip_atomic_load(&rel[bid * 16], __ATOMIC_RELAXED,
                             __HIP_MEMORY_SCOPE_AGENT) < epoch)
      __builtin_amdgcn_s_sleep(4);
  }
  __syncthreads();
}

// ---------------- helpers ----------------
__device__ __forceinline__ float sigf(float x) {
  float cx = fminf(fmaxf(x, -30.f), 30.f);
  return 1.f / (1.f + __expf(-cx));
}
__device__ __forceinline__ float tanh_f(float x) {
  float cx = fminf(fmaxf(x, -15.f), 15.f);
  float e = __expf(2.f * cx);
  return (e - 1.f) / (e + 1.f);
}

// ---------------- fused GEMM + LSTM cell (R7: LDS-staged, 8x8 tiles) ------
// Block g owns 32 gate-cols (col = gate*8 + jj, j = g*8+jj).  Z = X·W for
// 32 b × 32 cols, K-reduced 16 ways across threads; z never leaves the block.
// X: [32][K] bypass (communicated).  WB: [K][32] contiguous, plain cached.
__device__ __forceinline__ void fused_block(
    const float* __restrict__ X, const int K, const float* __restrict__ WB,
    const int g, const float* __restrict__ bih, const float* __restrict__ bhh,
    float* __restrict__ cst, float* __restrict__ d0, const int s0,
    float* __restrict__ d1, const int s1, float* __restrict__ d2, const int s2,
    const int tid, float* __restrict__ sm) {
  float* Xs = sm;           // [128][36] (Xs[k][b]) = 4608
  float* Ws = sm + 4608;    // [128][36] (Ws[k][c]) = 4608
  const int cg = tid & 3, bg = (tid >> 2) & 3, ks = tid >> 4;  // 16-way K split
  float acc[8][8];
#pragma unroll
  for (int ci = 0; ci < 8; ++ci)
#pragma unroll
    for (int bi = 0; bi < 8; ++bi) acc[ci][bi] = 0.f;

  const int nc = K >> 7;
  const int kloc = tid & 127, brow = tid >> 7;
  const float* xb = X + (size_t)brow * K + kloc;
  float px[16];
  float4 pw[4];
#pragma unroll
  for (int i = 0; i < 16; ++i) px[i] = gload(xb + (size_t)(2 * i) * K);
#pragma unroll
  for (int j = 0; j < 4; ++j)
    pw[j] = *(const float4*)(WB + (size_t)tid * 4 + j * 1024);

#pragma unroll 1
  for (int c = 0; c < nc; ++c) {
    __syncthreads();
#pragma unroll
    for (int i = 0; i < 16; ++i) Xs[kloc * 36 + brow + 2 * i] = px[i];
#pragma unroll
    for (int j = 0; j < 4; ++j) {
      const int ff = tid + 256 * j;           // float4 index in chunk
      *(float4*)(Ws + (ff >> 3) * 36 + (ff & 7) * 4) = pw[j];
    }
    __syncthreads();
    if (c + 1 < nc) {
      const float* xb2 = xb + (c + 1) * 128;
#pragma unroll
      for (int i = 0; i < 16; ++i) px[i] = gload(xb2 + (size_t)(2 * i) * K);
      const float* wb2 = WB + (size_t)(c + 1) * 4096 + (size_t)tid * 4;
#pragma unroll
      for (int j = 0; j < 4; ++j) pw[j] = *(const float4*)(wb2 + j * 1024);
    }
#pragma unroll
    for (int i = 0; i < 8; ++i) {
      const int k = i * 16 + ks;
      const float4 wA = *(const float4*)(Ws + k * 36 + cg * 8);
      const float4 wBv = *(const float4*)(Ws + k * 36 + cg * 8 + 4);
      const float4 xA = *(const float4*)(Xs + k * 36 + bg * 8);
      const float4 xBv = *(const float4*)(Xs + k * 36 + bg * 8 + 4);
      const float wr[8] = {wA.x, wA.y, wA.z, wA.w, wBv.x, wBv.y, wBv.z, wBv.w};
      const float xr[8] = {xA.x, xA.y, xA.z, xA.w, xBv.x, xBv.y, xBv.z, xBv.w};
#pragma unroll
      for (int ci = 0; ci < 8; ++ci)
#pragma unroll
        for (int bi = 0; bi < 8; ++bi)
          acc[ci][bi] = fmaf(wr[ci], xr[bi], acc[ci][bi]);
    }
  }
  // intra-wave reduce over the 4 ks values resident in each wave
#pragma unroll
  for (int ci = 0; ci < 8; ++ci)
#pragma unroll
    for (int bi = 0; bi < 8; ++bi) {
      float v = acc[ci][bi];
      v += __shfl_xor(v, 16);
      v += __shfl_xor(v, 32);
      acc[ci][bi] = v;
    }
  __syncthreads();  // done reading Xs/Ws; overlay with reduction scratch
  float* red = sm;        // [1024 outputs][5] (stride 5 kills bank aliasing)
  float* zs = sm + 5120;  // [1024] = z[col][b]
  const int lane = tid & 63, wv = tid >> 6;
  if (lane < 16) {  // lanes holding the wave-summed tiles
#pragma unroll
    for (int ci = 0; ci < 8; ++ci)
#pragma unroll
      for (int bi = 0; bi < 8; ++bi)
        red[((cg * 8 + ci) * 32 + bg * 8 + bi) * 5 + wv] = acc[ci][bi];
  }
  __syncthreads();
#pragma unroll
  for (int m = 0; m < 4; ++m) {
    const int o = tid + 256 * m;
    zs[o] = red[o * 5] + red[o * 5 + 1] + red[o * 5 + 2] + red[o * 5 + 3];
  }
  __syncthreads();
  // cell: 256 threads = 8 jj × 32 b
  const int b = tid & 31, jj = tid >> 5;
  const int j = g * 8 + jj;
  const float zi = zs[(0 * 8 + jj) * 32 + b] + bih[j] + bhh[j];
  const float zf = zs[(1 * 8 + jj) * 32 + b] + bih[1024 + j] + bhh[1024 + j];
  const float zg = zs[(2 * 8 + jj) * 32 + b] + bih[2048 + j] + bhh[2048 + j];
  const float zo = zs[(3 * 8 + jj) * 32 + b] + bih[3072 + j] + bhh[3072 + j];
  const float cp = cst[(size_t)b * 1024 + j];  // block-private: plain cached
  const float ct = sigf(zf) * cp + sigf(zi) * tanh_f(zg);
  const float h = sigf(zo) * tanh_f(ct);
  cst[(size_t)b * 1024 + j] = ct;
  gstore(d0 + (size_t)b * s0 + j, h);
  if (d1) gstore(d1 + (size_t)b * s1 + j, h);
  if (d2) gstore(d2 + (size_t)b * s2 + j, h);
}

// ---------------- setup kernels ----------------
__global__ __launch_bounds__(256) void k_small(
    const float* __restrict__ w1, const float* __restrict__ w2,
    const float* __restrict__ qw, const float* __restrict__ memw,
    const float* __restrict__ projw, const float* __restrict__ gatew,
    float* __restrict__ ws) {
  size_t i = (size_t)blockIdx.x * 256 + threadIdx.x;
  if (i < 20480) { size_t j = i & 255, m = i >> 8; ws[W1T + m * 256 + j] = w1[j * 80 + m]; return; }
  i -= 20480;
  if (i < 65536) { size_t j = i & 255, k = i >> 8; ws[W2T + k * 256 + j] = w2[j * 256 + k]; return; }
  i -= 65536;
  if (i < 131072) { size_t j = i & 127, k = i >> 7; ws[QWT + k * 128 + j] = qw[j * 1024 + k]; return; }
  i -= 131072;
  if (i < 65536) { size_t a = i & 127, e = i >> 7; ws[MEMWT + e * 128 + a] = memw[a * 512 + e]; return; }
  i -= 65536;
  if (i < 147456) {
    size_t o = i % 96, k = i / 96;
    float v = 0.f;
    if (o < 80) v = projw[o * 1536 + k];
    else if (o == 80) v = gatew[k];
    ws[PWT + k * 96 + o] = v;
  }
}

// weight transposes: input-indexed (coalesced reads, scattered writes)
__device__ __forceinline__ size_t att_out(int gcol, int kout) {
  const int gate = gcol >> 10, g = (gcol & 1023) >> 3, jj = gcol & 7;
  return WT_ATT + ((size_t)g * 1792 + kout) * 32 + gate * 8 + jj;
}
__device__ __forceinline__ size_t dec_out(int gcol, int kout) {
  const int gate = gcol >> 10, g = (gcol & 1023) >> 3, jj = gcol & 7;
  return WT_DEC + ((size_t)g * 2560 + kout) * 32 + gate * 8 + jj;
}
__global__ __launch_bounds__(256) void k_tr_a_wih(const float* __restrict__ w,
                                                  float* __restrict__ ws) {
  const int i = blockIdx.x * 256 + threadIdx.x;  // < 4096*768
  const int gcol = i / 768, k = i - gcol * 768;
  ws[att_out(gcol, k)] = w[i];
}
__global__ __launch_bounds__(256) void k_tr_a_whh(const float* __restrict__ w,
                                                  float* __restrict__ ws) {
  const int i = blockIdx.x * 256 + threadIdx.x;  // < 4096*1024
  const int gcol = i >> 10, kin = i & 1023;
  ws[att_out(gcol, 768 + kin)] = w[i];
}
__global__ __launch_bounds__(256) void k_tr_d_wih(const float* __restrict__ w,
                                                  float* __restrict__ ws) {
  const int i = blockIdx.x * 256 + threadIdx.x;  // < 4096*1536
  const int gcol = i / 1536, kin = i - gcol * 1536;
  const int kout = (kin < 1024) ? kin : kin + 1024;  // actx part -> 2048..2559
  ws[dec_out(gcol, kout)] = w[i];
}
__global__ __launch_bounds__(256) void k_tr_d_whh(const float* __restrict__ w,
                                                  float* __restrict__ ws) {
  const int i = blockIdx.x * 256 + threadIdx.x;  // < 4096*1024
  const int gcol = i >> 10, kin = i & 1023;
  ws[dec_out(gcol, 1024 + kin)] = w[i];
}

__global__ __launch_bounds__(256) void k_prenet(const float* __restrict__ din,
                                                float* __restrict__ ws) {
  __shared__ float h1[8][257];
  const int tg = blockIdx.x, b = blockIdx.y, j = threadIdx.x;
  float acc[8] = {0, 0, 0, 0, 0, 0, 0, 0};
  for (int m = 0; m < 80; ++m) {
    const float w = ws[W1T + m * 256 + j];
#pragma unroll
    for (int q = 0; q < 8; ++q) {
      const int t = tg * 8 + q;
      const float x = (t > 0) ? din[((size_t)b * 80 + m) * 800 + (t - 1)] : 0.f;
      acc[q] = fmaf(x, w, acc[q]);
    }
  }
#pragma unroll
  for (int q = 0; q < 8; ++q) h1[q][j] = fmaxf(acc[q], 0.f);
  __syncthreads();
  float a2[8] = {0, 0, 0, 0, 0, 0, 0, 0};
  for (int k = 0; k < 256; ++k) {
    const float w = ws[W2T + k * 256 + j];
#pragma unroll
    for (int q = 0; q < 8; ++q) a2[q] = fmaf(h1[q][k], w, a2[q]);
  }
#pragma unroll
  for (int q = 0; q < 8; ++q) {
    const int t = tg * 8 + q;
    ws[PREN_O + ((size_t)t * 32 + b) * 256 + j] = fmaxf(a2[q], 0.f);
  }
}

__global__ __launch_bounds__(256) void k_pmem(const float* __restrict__ mem,
                                              float* __restrict__ ws) {
  __shared__ float mt[16 * 516];
  const int b = blockIdx.x, tc = blockIdx.y, tid = threadIdx.x;
  const int ti0 = tc * 16;
  for (int i = tid; i < 16 * 128; i += 256) {
    const int r = i >> 7, c = i & 127;
    *(float4*)(mt + r * 516 + c * 4) =
        *(const float4*)(mem + ((size_t)b * 512 + ti0 + r) * 512 + c * 4);
  }
  __syncthreads();
  const int a = tid & 127, th = tid >> 7;
  float acc[8] = {0, 0, 0, 0, 0, 0, 0, 0};
  for (int e = 0; e < 512; ++e) {
    const float w = ws[MEMWT + (size_t)e * 128 + a];
#pragma unroll
    for (int q = 0; q < 8; ++q) acc[q] = fmaf(w, mt[(th * 8 + q) * 516 + e], acc[q]);
  }
#pragma unroll
  for (int q = 0; q < 8; ++q)
    ws[PMEMT + ((size_t)b * 128 + a) * 512 + ti0 + th * 8 + q] = acc[q];
}

// ---------------- main persistent kernel ----------------
struct TP {
  const float *mem, *abih, *abhh, *lconv, *llw, *vw, *dbih, *dbhh, *projb, *gateb;
  const int* lens;
  float* ws;
  float* out;
};

__global__ __launch_bounds__(256, 1) void taco_main(TP p) {
  __shared__ float smem[9472];
  float* const ws = p.ws;
  unsigned epoch = 0;
  const int bid = blockIdx.x, tid = threadIdx.x;

#pragma unroll 1
  for (int t = 0; t <= 800; ++t) {
    const int par = t & 1, nxt = (t + 1) & 1, prv = (t - 1) & 1;
    // ======== P1: att-fused(t) [0..127] | dec-fused(t-1) [128..255] ========
    if (bid < 128) {
      if (t < 800)
        fused_block(ws + XATT + (size_t)par * 57344, 1792,
                    ws + WT_ATT + (size_t)bid * 1792 * 32, bid,
                    p.abih, p.abhh, ws + AC_O,
                    ws + AH_O, 1024,
                    ws + XATT + (size_t)nxt * 57344 + 768, 1792,
                    ws + XDEC + (size_t)par * 81920, 2560, tid, smem);
    } else {
      if (t > 0)
        fused_block(ws + XDEC + (size_t)prv * 81920, 2560,
                    ws + WT_DEC + (size_t)(bid - 128) * 2560 * 32, bid - 128,
                    p.dbih, p.dbhh, ws + DC_O,
                    ws + DH_O, 1024,
                    ws + XDEC + (size_t)par * 81920 + 1024, 2560,
                    nullptr, 0, tid, smem);
    }
    gsync(ws, epoch);

    // ======== P2: energies(t) [0..127] | proj(t-1) [128..159] ========
    if (bid < 128) {
      if (t < 800) {
        const int b = bid >> 2, q = bid & 3;
        float* sa = smem;            // 1024 (ah)
        float* sloc = smem + 1024;   // 128*33
        float* pqp = smem + 5248;    // 256
        float* pq = smem + 5504;     // 128
        float* sme = smem + 5632;    // 256
#pragma unroll
        for (int i = 0; i < 4; ++i)
          sa[tid + 256 * i] = gload(ws + AH_O + (size_t)b * 1024 + tid + 256 * i);
#pragma unroll
        for (int ii = 0; ii < 16; ++ii) {
          const int flat = tid + 256 * ii;
          sloc[(flat >> 5) * 33 + (flat & 31)] =
              gload(ws + LOC_O + (size_t)b * 16384 + (size_t)q * 4096 + flat);
        }
        __syncthreads();
        {  // pq[j] = ah . qw[j], K split in 2
          const int j = tid & 127, kh = tid >> 7;
          float acc = 0;
          const float* qb = ws + QWT + (size_t)kh * 512 * 128 + j;
          const float* ab = sa + kh * 512;
          for (int k = 0; k < 512; ++k) acc = fmaf(qb[(size_t)k * 128], ab[k], acc);
          pqp[tid] = acc;
        }
        __syncthreads();
        if (tid < 128) pq[tid] = pqp[tid] + pqp[128 + tid];
        __syncthreads();
        const int ti_l = tid & 127, th = tid >> 7;
        float lr[32];
#pragma unroll
        for (int f = 0; f < 32; ++f) lr[f] = sloc[ti_l * 33 + f];
        const float* pmb =
            ws + PMEMT + (size_t)b * 65536 + (size_t)(th * 64) * 512 + q * 128 + ti_l;
        float acc_e = 0;
#pragma unroll 1
        for (int a0 = 0; a0 < 64; ++a0) {
          const int a = th * 64 + a0;
          float s = pq[a] + pmb[(size_t)a0 * 512];
          const float* la = p.llw + a * 32;
#pragma unroll
          for (int f = 0; f < 32; ++f) s = fmaf(lr[f], la[f], s);
          acc_e = fmaf(p.vw[a], tanh_f(s), acc_e);
        }
        sme[tid] = acc_e;
        __syncthreads();
        if (tid < 128) {
          const int ti = q * 128 + tid;
          const float e = sme[tid] + sme[128 + tid];
          gstore(ws + ENER_O + (size_t)b * 512 + ti, (ti < p.lens[b]) ? e : -1e9f);
        }
      }
    } else if (bid < 160) {
      if (t > 0) {  // proj(t-1) for b = bid-128: 81 outs, K=1536
        const int b = bid - 128;
        float* sx = smem;          // 1536
        float* sred = smem + 1536; // 256
#pragma unroll
        for (int i = 0; i < 6; ++i) {
          const int flat = tid + 256 * i;
          sx[flat] = (flat < 1024)
                         ? gload(ws + DH_O + (size_t)b * 1024 + flat)
                         : gload(ws + ACTX_O + (size_t)prv * 16384 + (size_t)b * 512 +
                                 (flat - 1024));
        }
        __syncthreads();
        float part = 0.f;
        const int o = tid / 3, ks = tid - o * 3;
        if (o < 81) {
          const float* wcol = ws + PWT + o;
          const int k0 = ks * 512;
          for (int k = k0; k < k0 + 512; ++k)
            part = fmaf(sx[k], wcol[(size_t)k * 96], part);
        }
        sred[tid] = part;
        __syncthreads();
        if (tid < 81) {
          float ssum = sred[tid * 3] + sred[tid * 3 + 1] + sred[tid * 3 + 2];
          ssum += (tid < 80) ? p.projb[tid] : p.gateb[0];
          if (tid < 80)
            p.out[MEL_OUT + ((size_t)b * 80 + tid) * 800 + (t - 1)] = ssum;
          else
            p.out[GATE_OUT + (size_t)b * 800 + (t - 1)] = ssum;
        }
      }
    }
    gsync(ws, epoch);

    // ======== P3: softmax + context + awc + conv(t+1)  [all 256] ========
    if (t < 800) {
      const int b = bid >> 3, dc8 = bid & 7;
      float* se = smem;           // 512
      float* red = smem + 512;    // 256
      float* sp = smem + 768;     // 512
      float* sc = smem + 1280;    // 256
      float* saw = smem + 1536;   // 128 (aw halo)
      float* sawh = smem + 1664;  // 128 (awc_new halo)
      float* slc = smem + 1792;   // 1984 (conv weights)
      se[tid] = gload(ws + ENER_O + (size_t)b * 512 + tid);
      se[256 + tid] = gload(ws + ENER_O + (size_t)b * 512 + 256 + tid);
      for (int i = tid; i < 1984; i += 256) slc[i] = p.lconv[i];
      __syncthreads();
      red[tid] = fmaxf(se[tid], se[256 + tid]);
      __syncthreads();
      for (int s = 128; s > 0; s >>= 1) {
        if (tid < s) red[tid] = fmaxf(red[tid], red[tid + s]);
        __syncthreads();
      }
      const float mx = red[0];
      __syncthreads();
      const float p0 = __expf(se[tid] - mx), p1 = __expf(se[256 + tid] - mx);
      sp[tid] = p0;
      sp[256 + tid] = p1;
      red[tid] = p0 + p1;
      __syncthreads();
      for (int s = 128; s > 0; s >>= 1) {
        if (tid < s) red[tid] += red[tid + s];
        __syncthreads();
      }
      const float inv = 1.f / red[0];
      // context: this block covers d in [dc8*64, +64)
      const int tseg = tid >> 6, dl = tid & 63;
      const float* mrow = p.mem + ((size_t)b * 512 + tseg * 128) * 512 + dc8 * 64 + dl;
      float acc = 0;
      for (int i = 0; i < 128; ++i)
        acc = fmaf(sp[tseg * 128 + i], mrow[(size_t)i * 512], acc);
      sc[tid] = acc;
      // aw / awc_new halo for conv
      const int base = dc8 * 64;
      for (int i = tid; i < 95; i += 256) {
        const int x = base - 15 + i;
        const bool ok = (unsigned)x < 512u;
        const float awx = ok ? sp[x] * inv : 0.f;
        saw[i] = awx;
        sawh[i] = awx + (ok ? gload(ws + AWC_O + (size_t)par * 16384 +
                                    (size_t)b * 512 + x)
                            : 0.f);
      }
      __syncthreads();
      if (tid < 64) {
        const float v = (sc[tid] + sc[64 + tid] + sc[128 + tid] + sc[192 + tid]) * inv;
        const int dd = base + tid;
        gstore(ws + ACTX_O + (size_t)par * 16384 + (size_t)b * 512 + dd, v);
        gstore(ws + XATT + (size_t)nxt * 57344 + (size_t)b * 1792 + 256 + dd, v);
        gstore(ws + XDEC + (size_t)par * 81920 + (size_t)b * 2560 + 2048 + dd, v);
        gstore(ws + AWC_O + (size_t)nxt * 16384 + (size_t)b * 512 + dd, sawh[15 + tid]);
        p.out[ALIGN_OUT + ((size_t)b * 800 + t) * 512 + dd] = sp[dd] * inv;
      }
      if (t + 1 < 800) {
        // conv for step t+1 over this block's t_in slice
        const int f = tid & 31, tig = tid >> 5;
#pragma unroll 1
        for (int tt = 0; tt < 8; ++tt) {
          const int til = tig + tt * 8;
          float a2 = 0;
#pragma unroll
          for (int k2 = 0; k2 < 31; ++k2) a2 = fmaf(saw[til + k2], slc[f * 62 + k2], a2);
#pragma unroll
          for (int k2 = 0; k2 < 31; ++k2)
            a2 = fmaf(sawh[til + k2], slc[f * 62 + 31 + k2], a2);
          gstore(ws + LOC_O + (size_t)b * 16384 + (size_t)(base + til) * 32 + f, a2);
        }
        // pren(t+1) -> XATT[nxt]
        if (dc8 < 4 && tid < 64) {
          const int cc = dc8 * 64 + tid;
          gstore(ws + XATT + (size_t)nxt * 57344 + (size_t)b * 1792 + cc,
                 ws[PREN_O + ((size_t)(t + 1) * 32 + b) * 256 + cc]);
        }
      }
    }
    gsync(ws, epoch);
  }
}

// ---------------- launch ----------------
extern "C" void kernel_launch(void* const* d_in, const int* in_sizes, int n_in,
                              void* d_out, int out_size, void* d_ws, size_t ws_size,
                              hipStream_t stream) {
  (void)in_sizes; (void)n_in; (void)out_size; (void)ws_size;
  const float* mem = (const float*)d_in[0];
  const float* decin = (const float*)d_in[1];
  const float* w1 = (const float*)d_in[2];
  const float* w2 = (const float*)d_in[3];
  const float* awih = (const float*)d_in[4];
  const float* awhh = (const float*)d_in[5];
  const float* abih = (const float*)d_in[6];
  const float* abhh = (const float*)d_in[7];
  const float* qw = (const float*)d_in[8];
  const float* memw = (const float*)d_in[9];
  const float* vw = (const float*)d_in[10];
  const float* lconv = (const float*)d_in[11];
  const float* llw = (const float*)d_in[12];
  const float* dwih = (const float*)d_in[13];
  const float* dwhh = (const float*)d_in[14];
  const float* dbih = (const float*)d_in[15];
  const float* dbhh = (const float*)d_in[16];
  const float* projw = (const float*)d_in[17];
  const float* projb = (const float*)d_in[18];
  const float* gatew = (const float*)d_in[19];
  const float* gateb = (const float*)d_in[20];
  const int* lens = (const int*)d_in[21];
  float* ws = (float*)d_ws;
  float* out = (float*)d_out;

  // zero: X buffers (pren(0)=0, ah(-1)=0, dh(-1)=0, actx(-1)=0),
  // state AH..DC, AWC, ACTX, ENER, LOC, and barrier lines.
  hipMemsetAsync(ws + XATT, 0, (114688 + 163840) * sizeof(float), stream);
  hipMemsetAsync(ws + AH_O, 0, 737280 * sizeof(float), stream);
  hipMemsetAsync(ws + BAR_O, 0, 4224 * sizeof(unsigned), stream);

  k_small<<<1680, 256, 0, stream>>>(w1, w2, qw, memw, projw, gatew, ws);
  k_tr_a_wih<<<12288, 256, 0, stream>>>(awih, ws);
  k_tr_a_whh<<<16384, 256, 0, stream>>>(awhh, ws);
  k_tr_d_wih<<<24576, 256, 0, stream>>>(dwih, ws);
  k_tr_d_whh<<<16384, 256, 0, stream>>>(dwhh, ws);
  k_prenet<<<dim3(100, 32), 256, 0, stream>>>(decin, ws);
  k_pmem<<<dim3(32, 32), 256, 0, stream>>>(mem, ws);

  TP tp{mem, abih, abhh, lconv, llw, vw, dbih, dbhh, projb, gateb, lens, ws, out};
  taco_main<<<256, 256, 0, stream>>>(tp);
}